// Round 1
// 1321.369 us; speedup vs baseline: 1.1218x; 1.1218x over previous
//
#include <hip/hip_runtime.h>
#include <stdint.h>

// ============================================================================
// StrategyAwareStringScalarOps — fused bf16-MFMA, 2-launch pipeline.
//
//   k_prep : top-4 + softmax weights (wave-parallel register top-k) ;
//            blocks 1..480 repack six weight matrices f32 -> bf16 in
//            B-fragment-native layout [ct][kkTot][lane][8].   (unchanged)
//   k_main : R2 change — k_gather is GONE. One block = 64 rows
//            (16 batches x 4 topk slots), 512 threads (8 waves), 128 KB LDS.
//            Phase P0 gathers s/c rows (f32, read once from HBM), converts,
//            and stages s,c,s*c as A-fragments in LDS. Phases P1..P6 run the
//            6-GEMM chain entirely through fragment-native LDS buffers
//            (lane-linear ds_read_b128 -> no stride-512B bank conflicts),
//            with 4x32KB regions overlaid by liveness:
//              R0: sC -> CF -> LN-reduce scratch
//              R1: X1 -> DF
//              R2: sS -> X2 -> Y[0:half]
//              R3: sP       -> Y[half:]
//            M=64 (vs 32) halves per-row B-weight L2 traffic (7.9->3.9 GB).
// ============================================================================

typedef __attribute__((ext_vector_type(8))) short frag8;   // 8 x bf16
typedef __attribute__((ext_vector_type(4))) float f4;
typedef __attribute__((ext_vector_type(4))) int   i4;

#define MFMA16(a,b,c) __builtin_amdgcn_mfma_f32_16x16x32_bf16((a),(b),(c),0,0,0)

__device__ __forceinline__ short f2bf(float x) {            // RNE f32 -> bf16
  unsigned u = __float_as_uint(x);
  return (short)((u + 0x7FFFu + ((u >> 16) & 1u)) >> 16);
}
__device__ __forceinline__ float bf2f(short s) {
  return __uint_as_float(((unsigned)(unsigned short)s) << 16);
}
__device__ __forceinline__ frag8 ldg8(const short* __restrict__ p) {
  return *reinterpret_cast<const frag8*>(p);
}

// ---------------------------------------------------------------------------
// Workspace layout (bytes):
//   0        : float wts[4] ; int ti[4] @ 16 ; int tj[4] @ 32
//   256      : w1p  (768x256 bf16)   393216
//   393472   : w2p  (256x256)        131072
//   524544   : dw1p (512x256)        262144
//   786688   : dw2p (256x256)        131072
//   917760   : fw1p (768x512)        786432
//   1704192  : fw2p (512x256)        262144   (end ~1.97 MB; gather bufs gone)
// ---------------------------------------------------------------------------

__global__ __launch_bounds__(256) void k_prep(
    const float* __restrict__ ps, const float* __restrict__ tempp,
    const float* __restrict__ w1, const float* __restrict__ w2,
    const float* __restrict__ dw1, const float* __restrict__ dw2,
    const float* __restrict__ fw1, const float* __restrict__ fw2,
    short* __restrict__ w1p, short* __restrict__ w2p,
    short* __restrict__ dw1p, short* __restrict__ dw2p,
    short* __restrict__ fw1p, short* __restrict__ fw2p,
    float* __restrict__ hdrf, int* __restrict__ hdri)
{
  if (blockIdx.x == 0) {
    // ---- wave-parallel top-4 of 120 scores, all in registers ----
    const int lane = threadIdx.x;
    if (lane < 64) {
      const float NEG = -3.4e38f;
      float v0 = (lane < 120)      ? ps[lane]      : NEG;
      float v1 = (lane + 64 < 120) ? ps[lane + 64] : NEG;
      const int i0 = lane, i1 = lane + 64;
      unsigned elim = 0;
      float tv[4]; int bi[4];
      #pragma unroll
      for (int t = 0; t < 4; ++t) {
        float c0 = (elim & 1u) ? NEG : v0;
        float c1 = (elim & 2u) ? NEG : v1;
        float cv; int ci;
        if (c1 > c0) { cv = c1; ci = i1; } else { cv = c0; ci = i0; }
        #pragma unroll
        for (int off = 32; off >= 1; off >>= 1) {
          float ov = __shfl_xor(cv, off, 64);
          int   oi = __shfl_xor(ci, off, 64);
          if (ov > cv || (ov == cv && oi < ci)) { cv = ov; ci = oi; }
        }
        tv[t] = cv; bi[t] = ci;               // all lanes agree now
        if (ci == i0) elim |= 1u;
        if (ci == i1) elim |= 2u;
      }
      if (lane == 0) {
        float tmp = fmaxf(tempp[0], 0.1f);
        float mx = tv[0];
        float e[4], s = 0.f;
        #pragma unroll
        for (int t = 0; t < 4; ++t) { e[t] = __expf((tv[t] - mx) / tmp); s += e[t]; }
        #pragma unroll
        for (int t = 0; t < 4; ++t) {
          hdrf[t]     = e[t] / s;
          hdri[4 + t] = bi[t] / 20;   // ti
          hdri[8 + t] = bi[t] % 20;   // tj
        }
      }
    }
    return;
  }
  // ---- weight repack: one thread = one 16B B-fragment (8 elems) ----
  int u = (blockIdx.x - 1) * 256 + threadIdx.x;   // 0 .. 122879
  const float* W; short* O; int N, KK;
  if      (u < 24576) {             W = w1;  O = w1p;  N = 256; KK = 24; }
  else if (u < 32768) { u -= 24576; W = w2;  O = w2p;  N = 256; KK = 8;  }
  else if (u < 49152) { u -= 32768; W = dw1; O = dw1p; N = 256; KK = 16; }
  else if (u < 57344) { u -= 49152; W = dw2; O = dw2p; N = 256; KK = 8;  }
  else if (u < 106496){ u -= 57344; W = fw1; O = fw1p; N = 512; KK = 24; }
  else                { u -= 106496;W = fw2; O = fw2p; N = 256; KK = 16; }
  int lane = u & 63, rest = u >> 6;
  int kk = rest % KK, ct = rest / KK;
  int k0 = kk * 32 + (lane >> 4) * 8;
  int n  = ct * 16 + (lane & 15);
  frag8 f;
  #pragma unroll
  for (int j = 0; j < 8; ++j) f[j] = f2bf(W[(size_t)(k0 + j) * N + n]);
  *reinterpret_cast<frag8*>(O + (size_t)u * 8) = f;
}

// ---------------------------------------------------------------------------
// k_main: 2048 blocks x 512 threads, 128 KB LDS (1 block/CU).
// Fragment-native LDS layout: elem(row,col) of a [64 x 32*KKS] tile lives at
//   buf[((T*KKS + kkf)*64 + lnq*16 + r15)*8 + j]
//   T=row>>4, r15=row&15, kkf=col>>5, lnq=(col>>3)&3, j=col&7
// so reader frag(T,kk,lane) = ds_read_b128 at ((T*KKS+kk)*64+lane)*16 bytes
// (lane-linear -> conflict-free).
// ---------------------------------------------------------------------------

__global__ __launch_bounds__(512, 2) void k_main(
    const float* __restrict__ sEnc, const float* __restrict__ cEnc,
    const int* __restrict__ hdri,  const float* __restrict__ hdrf,
    const short* __restrict__ w1p,  const short* __restrict__ w2p,
    const short* __restrict__ dw1p, const short* __restrict__ dw2p,
    const short* __restrict__ fw1p, const short* __restrict__ fw2p,
    const float* __restrict__ cm_b1, const float* __restrict__ cm_b2,
    const float* __restrict__ df_b1, const float* __restrict__ df_b2,
    const float* __restrict__ fu_b1, const float* __restrict__ fu_b2,
    const float* __restrict__ ln_g,  const float* __restrict__ ln_b,
    float* __restrict__ out)
{
  __shared__ __align__(16) short lds[65536];   // 128 KB
  short* R0 = lds;           // sC -> CF -> (float) LN scratch
  short* R1 = lds + 16384;   // X1 -> DF
  short* R2 = lds + 32768;   // sS -> X2 -> Y low half
  short* R3 = lds + 49152;   // sP       -> Y high half

  const int tid  = threadIdx.x;
  const int wv   = tid >> 6;        // wave 0..7 -> 32-col (or 64-col) strip
  const int lane = tid & 63;
  const int m15  = lane & 15;
  const int q    = lane >> 4;
  const int blk  = blockIdx.x;
  const int row0 = blk * 64;        // 64 rows = 16 batches x 4 slots
  const f4 fz = {0.f, 0.f, 0.f, 0.f};

  // ---------------- P0: gather s,c + products -> LDS A-fragments -----------
  {
    const int slot = m15 & 3;                       // row&3 is m15&3 here
    const int ti = hdri[4 + slot], tj = hdri[8 + slot];
    const int k0 = wv * 32 + q * 8;                 // thread's fixed kk = wv
    #pragma unroll
    for (int i = 0; i < 4; ++i) {                   // tile T = i
      int row = row0 + i * 16 + m15;
      int b = row >> 2;
      const float* sp = sEnc + ((size_t)b * 6  + ti) * 256 + k0;
      const float* cp = cEnc + ((size_t)b * 20 + tj) * 256 + k0;
      f4 sA = *(const f4*)sp, sB = *(const f4*)(sp + 4);
      f4 cA = *(const f4*)cp, cB = *(const f4*)(cp + 4);
      frag8 fs, fc, fp;
      #pragma unroll
      for (int j = 0; j < 8; ++j) {
        float sv = (j < 4) ? sA[j] : sB[j - 4];
        float cv = (j < 4) ? cA[j] : cB[j - 4];
        fs[j] = f2bf(sv); fc[j] = f2bf(cv); fp[j] = f2bf(sv * cv);
      }
      int off = ((i * 8 + wv) * 64 + lane) * 8;
      *reinterpret_cast<frag8*>(R2 + off) = fs;
      *reinterpret_cast<frag8*>(R0 + off) = fc;
      *reinterpret_cast<frag8*>(R3 + off) = fp;
    }
  }
  __syncthreads();                                   // sync0

  // epilogue writer for N=256 phases: acc[4][2] -> fragment-native buffer
  auto epiN256 = [&](const f4 (&acc)[4][2], const float* __restrict__ bias,
                     bool relu, short* __restrict__ dst) {
    #pragma unroll
    for (int c = 0; c < 2; ++c) {
      int col = wv * 32 + c * 16 + m15;
      float bv = bias[col];
      int kkf = col >> 5;                            // == wv
      int lnq = (col >> 3) & 3;
      int j   = col & 7;
      #pragma unroll
      for (int t = 0; t < 4; ++t) {
        #pragma unroll
        for (int r = 0; r < 4; ++r) {
          float x = acc[t][c][r] + bv;
          if (relu) x = fmaxf(x, 0.f);
          dst[((t * 8 + kkf) * 64 + lnq * 16 + q * 4 + r) * 8 + j] = f2bf(x);
        }
      }
    }
  };

  // ---------------- P1: X1 = relu([s|c|s*c] @ cm_w1 + b1) -> R1 ------------
  {
    f4 acc[4][2];
    #pragma unroll
    for (int t = 0; t < 4; ++t) { acc[t][0] = fz; acc[t][1] = fz; }
    #pragma unroll
    for (int kk = 0; kk < 8; ++kk) {
      frag8 as[4], ac[4], ap[4];
      #pragma unroll
      for (int t = 0; t < 4; ++t) {
        int off = ((t * 8 + kk) * 64 + lane) * 8;
        as[t] = *reinterpret_cast<const frag8*>(R2 + off);
        ac[t] = *reinterpret_cast<const frag8*>(R0 + off);
        ap[t] = *reinterpret_cast<const frag8*>(R3 + off);
      }
      #pragma unroll
      for (int c = 0; c < 2; ++c) {
        int ct = wv * 2 + c;
        frag8 b0 = ldg8(w1p + ((size_t)(ct * 24 +      kk) * 64 + lane) * 8);
        frag8 b1 = ldg8(w1p + ((size_t)(ct * 24 +  8 + kk) * 64 + lane) * 8);
        frag8 b2 = ldg8(w1p + ((size_t)(ct * 24 + 16 + kk) * 64 + lane) * 8);
        #pragma unroll
        for (int t = 0; t < 4; ++t) {
          acc[t][c] = MFMA16(as[t], b0, acc[t][c]);
          acc[t][c] = MFMA16(ac[t], b1, acc[t][c]);
          acc[t][c] = MFMA16(ap[t], b2, acc[t][c]);
        }
      }
    }
    epiN256(acc, cm_b1, true, R1);   // R1 fresh: no pre-write sync needed
  }

  // ---------------- P2: X2 = relu([d | |d|] @ df_w1 + b1) -> R2 ------------
  {
    f4 acc[4][2];
    #pragma unroll
    for (int t = 0; t < 4; ++t) { acc[t][0] = fz; acc[t][1] = fz; }
    #pragma unroll
    for (int kk = 0; kk < 8; ++kk) {
      frag8 dfr[4], efr[4];
      #pragma unroll
      for (int t = 0; t < 4; ++t) {
        int off = ((t * 8 + kk) * 64 + lane) * 8;
        frag8 s = *reinterpret_cast<const frag8*>(R2 + off);
        frag8 c = *reinterpret_cast<const frag8*>(R0 + off);
        frag8 d;
        #pragma unroll
        for (int j = 0; j < 8; ++j) d[j] = f2bf(bf2f(s[j]) - bf2f(c[j]));
        i4 ai = __builtin_bit_cast(i4, d);
        #pragma unroll
        for (int jj = 0; jj < 4; ++jj) ai[jj] &= 0x7FFF7FFF;
        dfr[t] = d;
        efr[t] = __builtin_bit_cast(frag8, ai);
      }
      #pragma unroll
      for (int c = 0; c < 2; ++c) {
        int ct = wv * 2 + c;
        frag8 bd = ldg8(dw1p + ((size_t)(ct * 16 +     kk) * 64 + lane) * 8);
        frag8 be = ldg8(dw1p + ((size_t)(ct * 16 + 8 + kk) * 64 + lane) * 8);
        #pragma unroll
        for (int t = 0; t < 4; ++t) {
          acc[t][c] = MFMA16(dfr[t], bd, acc[t][c]);
          acc[t][c] = MFMA16(efr[t], be, acc[t][c]);
        }
      }
    }
    __syncthreads();                 // sync1: all P1/P2 reads of R2,R0 done
    epiN256(acc, df_b1, true, R2);   // X2 overwrites sS
    __syncthreads();                 // sync2: X2 visible before P4
  }

  // ---------------- P3: CF = X1 @ cm_w2 + b2 -> R0 -------------------------
  {
    f4 acc[4][2];
    #pragma unroll
    for (int t = 0; t < 4; ++t) { acc[t][0] = fz; acc[t][1] = fz; }
    #pragma unroll
    for (int kk = 0; kk < 8; ++kk) {
      frag8 a[4];
      #pragma unroll
      for (int t = 0; t < 4; ++t)
        a[t] = *reinterpret_cast<const frag8*>(R1 + ((t * 8 + kk) * 64 + lane) * 8);
      #pragma unroll
      for (int c = 0; c < 2; ++c) {
        frag8 b = ldg8(w2p + ((size_t)((wv * 2 + c) * 8 + kk) * 64 + lane) * 8);
        #pragma unroll
        for (int t = 0; t < 4; ++t) acc[t][c] = MFMA16(a[t], b, acc[t][c]);
      }
    }
    // R0 (sC) is dead for every wave (they all passed sync1) -> write CF now.
    epiN256(acc, cm_b2, false, R0);
  }

  // ---------------- P4: DF = X2 @ df_w2 + b2 -> R1 -------------------------
  {
    f4 acc[4][2];
    #pragma unroll
    for (int t = 0; t < 4; ++t) { acc[t][0] = fz; acc[t][1] = fz; }
    #pragma unroll
    for (int kk = 0; kk < 8; ++kk) {
      frag8 a[4];
      #pragma unroll
      for (int t = 0; t < 4; ++t)
        a[t] = *reinterpret_cast<const frag8*>(R2 + ((t * 8 + kk) * 64 + lane) * 8);
      #pragma unroll
      for (int c = 0; c < 2; ++c) {
        frag8 b = ldg8(dw2p + ((size_t)((wv * 2 + c) * 8 + kk) * 64 + lane) * 8);
        #pragma unroll
        for (int t = 0; t < 4; ++t) acc[t][c] = MFMA16(a[t], b, acc[t][c]);
      }
    }
    __syncthreads();                 // sync3: all P3 reads of R1 (X1) done
    epiN256(acc, df_b2, false, R1);  // DF overwrites X1
    __syncthreads();                 // sync4: CF+DF visible before P5
  }

  // ------- P5: Y = relu([CF|DF|prod] @ fu_w1 + b1) -> R2+R3 (64x512) -------
  {
    f4 acc[4][4];
    #pragma unroll
    for (int t = 0; t < 4; ++t)
      #pragma unroll
      for (int c = 0; c < 4; ++c) acc[t][c] = fz;
    #pragma unroll
    for (int kk = 0; kk < 8; ++kk) {
      frag8 aF[4], aD[4], aP[4];
      #pragma unroll
      for (int t = 0; t < 4; ++t) {
        int off = ((t * 8 + kk) * 64 + lane) * 8;
        aF[t] = *reinterpret_cast<const frag8*>(R0 + off);
        aD[t] = *reinterpret_cast<const frag8*>(R1 + off);
        aP[t] = *reinterpret_cast<const frag8*>(R3 + off);
      }
      #pragma unroll
      for (int c = 0; c < 4; ++c) {
        int ct = wv * 4 + c;
        frag8 b0 = ldg8(fw1p + ((size_t)(ct * 24 +      kk) * 64 + lane) * 8);
        frag8 b1 = ldg8(fw1p + ((size_t)(ct * 24 +  8 + kk) * 64 + lane) * 8);
        frag8 b2 = ldg8(fw1p + ((size_t)(ct * 24 + 16 + kk) * 64 + lane) * 8);
        #pragma unroll
        for (int t = 0; t < 4; ++t) {
          acc[t][c] = MFMA16(aF[t], b0, acc[t][c]);
          acc[t][c] = MFMA16(aD[t], b1, acc[t][c]);
          acc[t][c] = MFMA16(aP[t], b2, acc[t][c]);
        }
      }
    }
    __syncthreads();                 // sync5: all P5 reads (R0,R1,R3) done
    // Y fragment-native, KKS=16, base R2 (spans R2..end of lds)
    #pragma unroll
    for (int c = 0; c < 4; ++c) {
      int col = wv * 64 + c * 16 + m15;
      float bv = fu_b1[col];
      int kkf = col >> 5;
      int lnq = (col >> 3) & 3;
      int j   = col & 7;
      #pragma unroll
      for (int t = 0; t < 4; ++t) {
        #pragma unroll
        for (int r = 0; r < 4; ++r) {
          float x = fmaxf(acc[t][c][r] + bv, 0.f);
          R2[((t * 16 + kkf) * 64 + lnq * 16 + q * 4 + r) * 8 + j] = f2bf(x);
        }
      }
    }
    __syncthreads();                 // sync6: Y visible
  }

  // ------- P6: fused = Y @ fu_w2 + b2 ; LayerNorm ; weighted sum -----------
  {
    f4 acc[4][2];
    #pragma unroll
    for (int t = 0; t < 4; ++t) { acc[t][0] = fz; acc[t][1] = fz; }
    #pragma unroll
    for (int kk = 0; kk < 16; ++kk) {
      frag8 a[4];
      #pragma unroll
      for (int t = 0; t < 4; ++t)
        a[t] = *reinterpret_cast<const frag8*>(R2 + ((t * 16 + kk) * 64 + lane) * 8);
      #pragma unroll
      for (int c = 0; c < 2; ++c) {
        frag8 b = ldg8(fw2p + ((size_t)((wv * 2 + c) * 16 + kk) * 64 + lane) * 8);
        #pragma unroll
        for (int t = 0; t < 4; ++t) acc[t][c] = MFMA16(a[t], b, acc[t][c]);
      }
    }
    // fused values: row = t*16 + q*4 + r, col = wv*32 + c*16 + m15
    float vals[4][2][4];
    #pragma unroll
    for (int c = 0; c < 2; ++c) {
      int col = wv * 32 + c * 16 + m15;
      float bv = fu_b2[col];
      #pragma unroll
      for (int t = 0; t < 4; ++t)
        #pragma unroll
        for (int r = 0; r < 4; ++r) vals[t][c][r] = acc[t][c][r] + bv;
    }
    // LN: in-lane over c (2 cols), shfl over 16 col-lanes, LDS over 8 waves
    float s1v[4][4], s2v[4][4];
    #pragma unroll
    for (int t = 0; t < 4; ++t) {
      #pragma unroll
      for (int r = 0; r < 4; ++r) {
        float a = 0.f, b = 0.f;
        #pragma unroll
        for (int c = 0; c < 2; ++c) { float v = vals[t][c][r]; a += v; b += v * v; }
        s1v[t][r] = a; s2v[t][r] = b;
      }
    }
    #pragma unroll
    for (int off = 8; off >= 1; off >>= 1) {
      #pragma unroll
      for (int t = 0; t < 4; ++t) {
        #pragma unroll
        for (int r = 0; r < 4; ++r) {
          s1v[t][r] += __shfl_xor(s1v[t][r], off, 64);
          s2v[t][r] += __shfl_xor(s2v[t][r], off, 64);
        }
      }
    }
    float* red = reinterpret_cast<float*>(R0);   // CF dead after sync6
    if (m15 == 0) {
      #pragma unroll
      for (int t = 0; t < 4; ++t) {
        #pragma unroll
        for (int r = 0; r < 4; ++r) {
          int row = t * 16 + q * 4 + r;
          red[(row * 8 + wv) * 2 + 0] = s1v[t][r];
          red[(row * 8 + wv) * 2 + 1] = s2v[t][r];
        }
      }
    }
    __syncthreads();                 // sync7
    float mu[4][4], rs[4][4];
    #pragma unroll
    for (int t = 0; t < 4; ++t) {
      #pragma unroll
      for (int r = 0; r < 4; ++r) {
        int row = t * 16 + q * 4 + r;
        float S1 = 0.f, S2 = 0.f;
        #pragma unroll
        for (int w = 0; w < 8; ++w) {
          S1 += red[(row * 8 + w) * 2];
          S2 += red[(row * 8 + w) * 2 + 1];
        }
        float m_ = S1 * (1.0f / 256.0f);
        float v_ = S2 * (1.0f / 256.0f) - m_ * m_;
        mu[t][r] = m_;
        rs[t][r] = rsqrtf(v_ + 1e-5f);
      }
    }
    // weighted sum over topk slots: rows 4g..4g+3 are regs r of one lane
    float wts[4] = {hdrf[0], hdrf[1], hdrf[2], hdrf[3]};
    #pragma unroll
    for (int c = 0; c < 2; ++c) {
      int col = wv * 32 + c * 16 + m15;
      float gv = ln_g[col], bv = ln_b[col];
      #pragma unroll
      for (int t = 0; t < 4; ++t) {
        float o = 0.f;
        #pragma unroll
        for (int r = 0; r < 4; ++r) {
          float rel = (vals[t][c][r] - mu[t][r]) * rs[t][r] * gv + bv;
          o += wts[r] * rel;
        }
        out[((size_t)(blk * 16 + t * 4 + q)) * 256 + col] = o;
      }
    }
  }
}

extern "C" void kernel_launch(void* const* d_in, const int* in_sizes, int n_in,
                              void* d_out, int out_size, void* d_ws, size_t ws_size,
                              hipStream_t stream)
{
  (void)in_sizes; (void)n_in; (void)out_size; (void)ws_size;
  const float* sEnc  = (const float*)d_in[0];
  const float* cEnc  = (const float*)d_in[1];
  const float* ps    = (const float*)d_in[2];
  const float* temp  = (const float*)d_in[3];
  const float* cm_w1 = (const float*)d_in[4];
  const float* cm_b1 = (const float*)d_in[5];
  const float* cm_w2 = (const float*)d_in[6];
  const float* cm_b2 = (const float*)d_in[7];
  const float* df_w1 = (const float*)d_in[8];
  const float* df_b1 = (const float*)d_in[9];
  const float* df_w2 = (const float*)d_in[10];
  const float* df_b2 = (const float*)d_in[11];
  const float* fu_w1 = (const float*)d_in[12];
  const float* fu_b1 = (const float*)d_in[13];
  const float* fu_w2 = (const float*)d_in[14];
  const float* fu_b2 = (const float*)d_in[15];
  const float* ln_g  = (const float*)d_in[16];
  const float* ln_b  = (const float*)d_in[17];

  char*  ws   = (char*)d_ws;
  float* hdrf = (float*)ws;
  int*   hdri = (int*)ws;
  short* w1p  = (short*)(ws + 256);
  short* w2p  = (short*)(ws + 393472);
  short* dw1p = (short*)(ws + 524544);
  short* dw2p = (short*)(ws + 786688);
  short* fw1p = (short*)(ws + 917760);
  short* fw2p = (short*)(ws + 1704192);
  float* out  = (float*)d_out;

  k_prep<<<481, 256, 0, stream>>>(ps, temp, cm_w1, cm_w2, df_w1, df_w2, fu_w1, fu_w2,
                                  w1p, w2p, dw1p, dw2p, fw1p, fw2p, hdrf, hdri);
  k_main<<<2048, 512, 0, stream>>>(sEnc, cEnc, hdri, hdrf,
                                   w1p, w2p, dw1p, dw2p, fw1p, fw2p,
                                   cm_b1, cm_b2, df_b1, df_b2, fu_b1, fu_b2,
                                   ln_g, ln_b, out);
}